// Round 13
// baseline (178.416 us; speedup 1.0000x reference)
//
#include <hip/hip_runtime.h>
#include <math.h>

#define NN 32000
#define PP 1000
#define KK 40
#define INC 64
#define DD 32
#define EPSV 1e-5

// ws BYTE offsets. Total ~22.4 MB.
#define OB_H64 0UL
#define OB_S64 8192000UL
#define OB_F32 8960000UL
#define OB_A32 13056000UL
#define OB_P1  21248000UL
#define OB_P2  21760000UL
#define OB_S32 21888000UL
#define OB_ST1 22400000UL
#define OB_ST2 22400512UL

__device__ __forceinline__ double elud(double v){ return v > 0.0 ? v : expm1(v); }
__device__ __forceinline__ float eluf(float v){ return v > 0.f ? v : expm1f(v); }

// pre-MLP in f64, 4 threads per node (each owns 8 output channels).
__global__ __launch_bounds__(128) void k_pre(const float* __restrict__ x,
    const float* __restrict__ w1, const float* __restrict__ b1,
    const float* __restrict__ w2, const float* __restrict__ b2,
    char* __restrict__ ws)
{
  __shared__ double lw1[INC*DD];
  __shared__ double lw2[DD*DD];
  __shared__ double lb1[DD], lb2[DD];
  __shared__ double wpart[2][64];
  int tid = threadIdx.x;
  int nodeBase = blockIdx.x * 32;
  for (int i = tid; i < INC*DD; i += 128) lw1[i] = (double)w1[i];
  for (int i = tid; i < DD*DD; i += 128) lw2[i] = (double)w2[i];
  if (tid < DD){ lb1[tid] = (double)b1[tid]; lb2[tid] = (double)b2[tid]; }
  __syncthreads();

  int nl = tid >> 2, q = tid & 3;
  int node = nodeBase + nl;
  const float* xr = x + (size_t)node * INC;
  double acc[8];
#pragma unroll
  for (int c = 0; c < 8; ++c) acc[c] = lb1[q*8 + c];
#pragma unroll 8
  for (int k = 0; k < INC; ++k){
    double xv = (double)xr[k];
#pragma unroll
    for (int c = 0; c < 8; ++c) acc[c] = fma(xv, lw1[k*DD + q*8 + c], acc[c]);
  }
  double h1o[8];
#pragma unroll
  for (int c = 0; c < 8; ++c) h1o[c] = elud(acc[c]);
  double h1f[DD];
#pragma unroll
  for (int b = 0; b < 4; ++b){
#pragma unroll
    for (int i = 0; i < 8; ++i)
      h1f[b*8 + i] = __shfl_xor(h1o[i], q ^ b);
  }
#pragma unroll
  for (int c = 0; c < 8; ++c) acc[c] = lb2[q*8 + c];
#pragma unroll 8
  for (int k = 0; k < DD; ++k){
    double hk = h1f[k];
#pragma unroll
    for (int c = 0; c < 8; ++c) acc[c] = fma(hk, lw2[k*DD + q*8 + c], acc[c]);
  }
  double h2[8];
#pragma unroll
  for (int c = 0; c < 8; ++c) h2[c] = elud(acc[c]);
  double* hT = (double*)(ws + OB_H64);
#pragma unroll
  for (int c = 0; c < 8; ++c) hT[(size_t)(q*8 + c)*NN + node] = h2[c];

  double s[8], qv[8];
#pragma unroll
  for (int i = 0; i < 8; ++i){ s[i] = h2[i]; qv[i] = h2[i]*h2[i]; }
#pragma unroll
  for (int o = 4; o <= 32; o <<= 1){
#pragma unroll
    for (int i = 0; i < 8; ++i){ s[i] += __shfl_xor(s[i], o); qv[i] += __shfl_xor(qv[i], o); }
  }
  int lane = tid & 63, wid = tid >> 6;
  if (lane < 4){
#pragma unroll
    for (int i = 0; i < 8; ++i){
      wpart[wid][lane*8 + i]      = s[i];
      wpart[wid][32 + lane*8 + i] = qv[i];
    }
  }
  __syncthreads();
  if (tid < 64)
    ((double*)(ws + OB_P1))[blockIdx.x*64 + tid] = wpart[0][tid] + wpart[1][tid];
}

__global__ __launch_bounds__(128) void k_stats(const double* __restrict__ part,
    double* __restrict__ stats, int nrows)
{
  __shared__ double ls[128], lq[128];
  int c = blockIdx.x;
  int t = threadIdx.x;
  double s = 0.0, q = 0.0;
  for (int r = t; r < nrows; r += 128){
    s += part[r*64 + c];
    q += part[r*64 + 32 + c];
  }
  ls[t] = s; lq[t] = q;
  __syncthreads();
  for (int o = 64; o > 0; o >>= 1){
    if (t < o){ ls[t] += ls[t+o]; lq[t] += lq[t+o]; }
    __syncthreads();
  }
  if (t == 0){
    double m = ls[0] / (double)NN;
    double qq = lq[0] / (double)NN;
    stats[c] = m;
    stats[32+c] = 1.0 / sqrt(qq - m*m + EPSV);
  }
}

// 2 threads/node: BN1 in-register, exact f64 s-chains, feat halves;
// s32 written as float4 (x,y,z,r).
__global__ __launch_bounds__(128) void k_sfeat(
    const float* __restrict__ sw, const float* __restrict__ sb,
    const float* __restrict__ hw, const float* __restrict__ hb,
    const float* __restrict__ g, const float* __restrict__ b,
    char* __restrict__ ws)
{
  __shared__ double lsw[DD*3], lsb[3], lstat[64], lgd[DD], lbd[DD];
  __shared__ float lhw[DD*DD], lhb[DD];
  int tid = threadIdx.x;
  for (int i = tid; i < DD*3; i += 128) lsw[i] = (double)sw[i];
  for (int i = tid; i < DD*DD; i += 128) lhw[i] = hw[i];
  if (tid < 3) lsb[tid] = (double)sb[tid];
  if (tid < DD){ lhb[tid] = hb[tid]; lgd[tid] = (double)g[tid]; lbd[tid] = (double)b[tid]; }
  if (tid >= 64 && tid < 128) lstat[tid-64] = ((const double*)(ws + OB_ST1))[tid-64];
  __syncthreads();
  int nl = tid >> 1, p = tid & 1;
  int node = blockIdx.x*64 + nl;
  const double* hT = (const double*)(ws + OB_H64);
  double ho[16];
#pragma unroll
  for (int i = 0; i < 16; ++i){
    int c = p*16 + i;
    double xv = hT[(size_t)c*NN + node];
    ho[i] = (xv - lstat[c]) * lstat[32+c] * lgd[c] + lbd[c];
  }
  double hf[DD];
#pragma unroll
  for (int i = 0; i < 16; ++i){
    double pr = __shfl_xor(ho[i], 1);
    hf[i]      = p ? pr : ho[i];
    hf[16 + i] = p ? ho[i] : pr;
  }
  double* sT = (double*)(ws + OB_S64);
  double v0 = 0.0, v1 = 0.0, v2 = 0.0;
  if (p == 0){
    double s0 = lsb[0], s2 = lsb[2];
#pragma unroll
    for (int k = 0; k < DD; ++k){
      s0 = fma(hf[k], lsw[k*3+0], s0);
      s2 = fma(hf[k], lsw[k*3+2], s2);
    }
    sT[node] = s0; sT[2*NN + node] = s2;
    v0 = s0; v2 = s2;
  } else {
    double s1 = lsb[1];
#pragma unroll
    for (int k = 0; k < DD; ++k) s1 = fma(hf[k], lsw[k*3+1], s1);
    sT[NN + node] = s1;
    v1 = s1;
  }
  {
    float f0 = (float)v0, f1 = (float)v1, f2 = (float)v2;
    float g0 = __shfl_xor(f0, 1);
    float g2 = __shfl_xor(f2, 1);
    if (p == 1){
      float r = fmaf(g2, g2, fmaf(f1, f1, g0*g0));
      ((float4*)(ws + OB_S32))[node] = make_float4(g0, f1, g2, r);
    }
  }
  float hv[DD];
#pragma unroll
  for (int c = 0; c < DD; ++c) hv[c] = (float)hf[c];
  float f[16];
#pragma unroll
  for (int i = 0; i < 16; ++i) f[i] = lhb[p*16 + i];
#pragma unroll 4
  for (int k = 0; k < DD; ++k){
    float hk = hv[k];
#pragma unroll
    for (int i = 0; i < 16; ++i) f[i] = fmaf(hk, lhw[k*DD + p*16 + i], f[i]);
  }
  float* frow = (float*)(ws + OB_F32) + (size_t)node*DD + p*16;
#pragma unroll
  for (int u = 0; u < 4; ++u)
    ((float4*)frow)[u] = make_float4(f[4*u], f[4*u+1], f[4*u+2], f[4*u+3]);
}

// one wave per query node. Stage A: f32 prefilter superset (window [40,58]).
// Stage B: exact f64 refine with fast paths (cnt==40 / cLE==40 / full).
__global__ __launch_bounds__(256) void k_knn(char* __restrict__ ws)
{
  __shared__ int   lds_cand[4][64];
  __shared__ int   lds_j[4][KK];
  __shared__ float lds_w[4][KK];
  const double* sT = (const double*)(ws + OB_S64);
  const float*  fp = (const float*)(ws + OB_F32);
  float* ap = (float*)(ws + OB_A32);
  int tid = threadIdx.x;
  int lane = tid & 63, wid = tid >> 6;
  int n = blockIdx.x * 4 + wid;
  int e = n / PP;
  int base = e * PP;
  const float4* s4 = (const float4*)(ws + OB_S32) + base;
  int nl = n - base;
  float4 qv = s4[nl];
  float m2x = -2.f*qv.x, m2y = -2.f*qv.y, m2z = -2.f*qv.z;
  float rq = qv.w;

  float d2f[16];
#pragma unroll
  for (int t = 0; t < 16; ++t){
    int j = lane + 64*t;
    float key = __builtin_inff();
    if (j < PP){
      float4 p = s4[j];
      float u = fmaf(p.x, m2x, p.w);
      u = fmaf(p.y, m2y, u);
      u = fmaf(p.z, m2z, u);
      key = fmaxf(u + rq, 0.f);
    }
    d2f[t] = key;
  }
  float lmin = d2f[0];
#pragma unroll
  for (int t = 1; t < 16; ++t) lmin = fminf(lmin, d2f[t]);
  float glo = lmin, ghi = lmin;
#pragma unroll
  for (int o = 32; o > 0; o >>= 1){
    glo = fminf(glo, __shfl_xor(glo, o));
    ghi = fmaxf(ghi, __shfl_xor(ghi, o));
  }
  unsigned lo = __float_as_uint(glo), hi = __float_as_uint(ghi);
  while (lo < hi){
    unsigned mid = lo + ((hi - lo) >> 1);
    float midf = __uint_as_float(mid);
    int c = 0;
#pragma unroll
    for (int t = 0; t < 16; ++t) c += __popcll(__ballot(d2f[t] <= midf));
    if (c >= KK){
      if (c <= 58){ lo = mid; break; }
      hi = mid;
    } else lo = mid + 1;
  }
  float T = __uint_as_float(lo) * 1.0015f + 4e-6f;

  unsigned long long lml = (1ull << lane) - 1ull;
  int cnt = 0;
#pragma unroll
  for (int t = 0; t < 16; ++t){
    bool sel = d2f[t] <= T;
    unsigned long long m = __ballot(sel);
    if (sel){
      int pos = cnt + __popcll(m & lml);
      if (pos < 64) lds_cand[wid][pos] = lane + 64*t;
    }
    cnt += __popcll(m);
  }
  if (cnt > 64) cnt = 64;

  double sx = sT[n], sy = sT[NN + n], sz = sT[2*NN + n];
  int jl = (lane < cnt) ? lds_cand[wid][lane] : -1;
  double d2l = __builtin_inf();
  if (jl >= 0){
    int jj = base + jl;
    double dx = sT[jj] - sx, dy = sT[NN + jj] - sy, dz = sT[2*NN + jj] - sz;
    d2l = (dx*dx + dy*dy) + dz*dz;   // np summation order (matches ref chain)
  }
  bool sel40;
  if (cnt == KK){
    sel40 = (jl >= 0);
  } else {
    unsigned long long bits = (unsigned long long)__double_as_longlong(d2l);
    unsigned khi = (unsigned)(bits >> 32);
    unsigned klo = (unsigned)bits;
    unsigned blo = (jl >= 0) ? khi : 0xFFFFFFFFu;
    unsigned bhi = (jl >= 0) ? khi : 0u;
#pragma unroll
    for (int o = 32; o > 0; o >>= 1){
      blo = min(blo, (unsigned)__shfl_xor((int)blo, o));
      bhi = max(bhi, (unsigned)__shfl_xor((int)bhi, o));
    }
    unsigned l1 = blo, h1 = bhi;
    while (l1 < h1){
      unsigned mid = l1 + ((h1 - l1) >> 1);
      int c = __popcll(__ballot(khi <= mid));
      if (c >= KK) h1 = mid; else l1 = mid + 1;
    }
    unsigned H2 = l1;
    int cLE = __popcll(__ballot(khi <= H2));
    if (cLE == KK){
      sel40 = (jl >= 0) && (khi <= H2);
    } else {
      int cLT = __popcll(__ballot(khi < H2));
      int r = KK - cLT;
      unsigned l2 = 0u, h2v = 0xFFFFFFFFu;
      while (l2 < h2v){
        unsigned mid = l2 + ((h2v - l2) >> 1);
        int c = __popcll(__ballot(khi == H2 && klo <= mid));
        if (c >= r) h2v = mid; else l2 = mid + 1;
      }
      unsigned L2v = l2;
      int cLT2 = __popcll(__ballot(khi == H2 && klo < L2v));
      int r2 = r - cLT2;
      bool dup = (khi == H2) && (klo == L2v);
      unsigned long long dupm = __ballot(dup);
      int rank = 0;
      if (dup){
        unsigned long long mm = dupm;
        while (mm){
          int l = __builtin_ctzll(mm);
          mm &= mm - 1;
          if (lds_cand[wid][l] < jl) rank++;
        }
      }
      sel40 = (khi < H2) || (khi == H2 && klo < L2v) || (dup && rank < r2);
    }
  }
  unsigned long long selm = __ballot(sel40);
  if (sel40){
    int pos = __popcll(selm & lml);
    lds_j[wid][pos] = jl;
    lds_w[wid][pos] = expf(-10.f * (float)d2l);
  }

  int half = lane >> 5, ch = lane & 31;
  float accm = 0.f, accx = -__builtin_inff();
#pragma unroll
  for (int c0 = 0; c0 < 2; ++c0){
    float fv[10], wv[10];
#pragma unroll
    for (int it = 0; it < 10; ++it){
      int si = 2*(c0*10 + it) + half;
      int j = lds_j[wid][si];
      wv[it] = lds_w[wid][si];
      fv[it] = fp[((base + j) << 5) + ch];
    }
#pragma unroll
    for (int it = 0; it < 10; ++it){
      float m = wv[it] * fv[it];
      accm += m;
      accx = fmaxf(accx, m);
    }
  }
  accm += __shfl_xor(accm, 32);
  accx = fmaxf(accx, __shfl_xor(accx, 32));
  if (lane < DD){
    ap[(size_t)n*64 + lane]      = accm * (1.f/KK);
    ap[(size_t)n*64 + DD + lane] = accx;
  }
}

// 1 thread/node. Weight indices are wave-uniform -> read weights/biases
// DIRECTLY from global (__restrict__ const): compiler emits scalar s_load
// (SMEM/SALU path), eliminating ~6240 ds_reads/wave of LDS staging.
// Arithmetic/order identical to round 12 -> bit-identical output.
__global__ __launch_bounds__(128) void k_post(
    const float* __restrict__ g, const float* __restrict__ b,
    const float* __restrict__ o1w, const float* __restrict__ o2w,
    const float* __restrict__ o2b,
    const float* __restrict__ p1w, const float* __restrict__ p1b,
    const float* __restrict__ p2w, const float* __restrict__ p2b,
    char* __restrict__ ws)
{
  __shared__ double lstat[64], lgd[DD], lbd[DD];
  __shared__ double wpart[2][64];
  int tid = threadIdx.x;
  if (tid < DD){ lgd[tid] = (double)g[tid]; lbd[tid] = (double)b[tid]; }
  if (tid >= 64 && tid < 128) lstat[tid-64] = ((const double*)(ws + OB_ST1))[tid-64];
  __syncthreads();
  int node = blockIdx.x*128 + tid;
  const double* hT = (const double*)(ws + OB_H64);
  float hv[DD];
#pragma unroll 4
  for (int c = 0; c < DD; ++c){
    double xv = hT[(size_t)c*NN + node];
    hv[c] = (float)((xv - lstat[c]) * lstat[32+c] * lgd[c] + lbd[c]);
  }
  float xg[DD];
#pragma unroll
  for (int c = 0; c < DD; ++c) xg[c] = o2b[c];
#pragma unroll 4
  for (int k = 0; k < DD; ++k){
    float hk = hv[k];
#pragma unroll
    for (int c = 0; c < DD; ++c) xg[c] = fmaf(hk, o1w[k*DD+c], xg[c]);
  }
  const float4* ar = (const float4*)((const float*)(ws + OB_A32) + (size_t)node*64);
#pragma unroll 2
  for (int k4 = 0; k4 < 16; ++k4){
    float4 a = ar[k4];
    float as[4] = {a.x, a.y, a.z, a.w};
#pragma unroll
    for (int u = 0; u < 4; ++u){
      int k = k4*4 + u;
#pragma unroll
      for (int c = 0; c < DD; ++c) xg[c] = fmaf(as[u], o2w[k*DD+c], xg[c]);
    }
  }
  float t1[DD];
#pragma unroll
  for (int c = 0; c < DD; ++c) t1[c] = p1b[c];
#pragma unroll 4
  for (int k = 0; k < DD; ++k){
    float v = xg[k];
#pragma unroll
    for (int c = 0; c < DD; ++c) t1[c] = fmaf(v, p1w[k*DD+c], t1[c]);
  }
  {
    const double* sT = (const double*)(ws + OB_S64);
    float s0 = (float)sT[node], s1 = (float)sT[NN+node], s2 = (float)sT[2*NN+node];
#pragma unroll
    for (int c = 0; c < DD; ++c){
      t1[c] = fmaf(s0, p1w[32*DD+c], t1[c]);
      t1[c] = fmaf(s1, p1w[33*DD+c], t1[c]);
      t1[c] = fmaf(s2, p1w[34*DD+c], t1[c]);
    }
  }
#pragma unroll 4
  for (int k = 0; k < DD; ++k){
    float v = hv[k];
#pragma unroll
    for (int c = 0; c < DD; ++c) t1[c] = fmaf(v, p1w[(35+k)*DD+c], t1[c]);
  }
#pragma unroll
  for (int c = 0; c < DD; ++c) t1[c] = eluf(t1[c]);
  float t2[DD];
#pragma unroll
  for (int c = 0; c < DD; ++c) t2[c] = p2b[c];
#pragma unroll 4
  for (int k = 0; k < DD; ++k){
    float v = t1[k];
#pragma unroll
    for (int c = 0; c < DD; ++c) t2[c] = fmaf(v, p2w[k*DD+c], t2[c]);
  }
#pragma unroll
  for (int c = 0; c < DD; ++c) t2[c] = eluf(t2[c]);
  float* tr = (float*)(ws + OB_F32) + (size_t)node*DD;
#pragma unroll
  for (int u = 0; u < 8; ++u)
    ((float4*)tr)[u] = make_float4(t2[4*u], t2[4*u+1], t2[4*u+2], t2[4*u+3]);

  int lane = tid & 63, wid = tid >> 6;
#pragma unroll
  for (int hlf = 0; hlf < 2; ++hlf){
    double s[16], q[16];
#pragma unroll
    for (int i = 0; i < 16; ++i){ double xv = (double)t2[hlf*16 + i]; s[i] = xv; q[i] = xv*xv; }
#pragma unroll
    for (int o = 32; o > 0; o >>= 1){
#pragma unroll
      for (int i = 0; i < 16; ++i){ s[i] += __shfl_xor(s[i], o); q[i] += __shfl_xor(q[i], o); }
    }
    if (lane == 0){
#pragma unroll
      for (int i = 0; i < 16; ++i){
        wpart[wid][hlf*16 + i] = s[i];
        wpart[wid][32 + hlf*16 + i] = q[i];
      }
    }
  }
  __syncthreads();
  if (tid < 64)
    ((double*)(ws + OB_P2))[blockIdx.x*64 + tid] = wpart[0][tid] + wpart[1][tid];
}

__global__ __launch_bounds__(256) void k_bnout(
    const float* __restrict__ g, const float* __restrict__ b,
    const char* __restrict__ ws, float* __restrict__ out)
{
  __shared__ float lstat[64], lg[DD], lb[DD];
  int tid = threadIdx.x;
  if (tid < 64) lstat[tid] = (float)((const double*)(ws + OB_ST2))[tid];
  if (tid >= 64 && tid < 96){ lg[tid-64] = g[tid-64]; lb[tid-64] = b[tid-64]; }
  __syncthreads();
  int node = blockIdx.x*256 + tid;
  const float4* tr = (const float4*)((const float*)(ws + OB_F32) + (size_t)node*DD);
  float4* orow = (float4*)(out + (size_t)node*DD);
#pragma unroll
  for (int i = 0; i < 8; ++i){
    float4 v = tr[i];
    float vv[4] = {v.x, v.y, v.z, v.w};
#pragma unroll
    for (int u = 0; u < 4; ++u){
      int c = 4*i + u;
      vv[u] = (vv[u] - lstat[c]) * lstat[32+c] * lg[c] + lb[c];
    }
    orow[i] = make_float4(vv[0], vv[1], vv[2], vv[3]);
  }
}

extern "C" void kernel_launch(void* const* d_in, const int* in_sizes, int n_in,
                              void* d_out, int out_size, void* d_ws, size_t ws_size,
                              hipStream_t stream)
{
  const float* x       = (const float*)d_in[0];
  const float* pre_w1  = (const float*)d_in[3];
  const float* pre_b1  = (const float*)d_in[4];
  const float* pre_w2  = (const float*)d_in[5];
  const float* pre_b2  = (const float*)d_in[6];
  const float* bn1_g   = (const float*)d_in[7];
  const float* bn1_b   = (const float*)d_in[8];
  const float* lin_s_w = (const float*)d_in[9];
  const float* lin_s_b = (const float*)d_in[10];
  const float* lin_h_w = (const float*)d_in[11];
  const float* lin_h_b = (const float*)d_in[12];
  const float* out1_w  = (const float*)d_in[13];
  const float* out2_w  = (const float*)d_in[14];
  const float* out2_b  = (const float*)d_in[15];
  const float* post_w1 = (const float*)d_in[16];
  const float* post_b1 = (const float*)d_in[17];
  const float* post_w2 = (const float*)d_in[18];
  const float* post_b2 = (const float*)d_in[19];
  const float* bn2_g   = (const float*)d_in[20];
  const float* bn2_b   = (const float*)d_in[21];
  char* ws  = (char*)d_ws;
  float* out = (float*)d_out;

  k_pre  <<<1000, 128, 0, stream>>>(x, pre_w1, pre_b1, pre_w2, pre_b2, ws);
  k_stats<<<32, 128, 0, stream>>>((const double*)(ws + OB_P1), (double*)(ws + OB_ST1), 1000);
  k_sfeat<<<500, 128, 0, stream>>>(lin_s_w, lin_s_b, lin_h_w, lin_h_b, bn1_g, bn1_b, ws);
  k_knn  <<<8000, 256, 0, stream>>>(ws);
  k_post <<<250, 128, 0, stream>>>(bn1_g, bn1_b, out1_w, out2_w, out2_b,
                                   post_w1, post_b1, post_w2, post_b2, ws);
  k_stats<<<32, 128, 0, stream>>>((const double*)(ws + OB_P2), (double*)(ws + OB_ST2), 250);
  k_bnout<<<125, 256, 0, stream>>>(bn2_g, bn2_b, ws, out);
}

// Round 14
// 166.035 us; speedup vs baseline: 1.0746x; 1.0746x over previous
//
#include <hip/hip_runtime.h>
#include <math.h>

#define NN 32000
#define PP 1000
#define KK 40
#define INC 64
#define DD 32
#define EPSV 1e-5

// ws BYTE offsets. Total ~22.4 MB.
#define OB_H64 0UL
#define OB_S64 8192000UL
#define OB_F32 8960000UL
#define OB_A32 13056000UL
#define OB_P1  21248000UL
#define OB_P2  21760000UL
#define OB_S32 21888000UL
#define OB_ST1 22400000UL
#define OB_ST2 22400512UL

__device__ __forceinline__ double elud(double v){ return v > 0.0 ? v : expm1(v); }
__device__ __forceinline__ float eluf(float v){ return v > 0.f ? v : expm1f(v); }

// pre-MLP in f64, 4 threads per node (each owns 8 output channels).
__global__ __launch_bounds__(128) void k_pre(const float* __restrict__ x,
    const float* __restrict__ w1, const float* __restrict__ b1,
    const float* __restrict__ w2, const float* __restrict__ b2,
    char* __restrict__ ws)
{
  __shared__ double lw1[INC*DD];
  __shared__ double lw2[DD*DD];
  __shared__ double lb1[DD], lb2[DD];
  __shared__ double wpart[2][64];
  int tid = threadIdx.x;
  int nodeBase = blockIdx.x * 32;
  for (int i = tid; i < INC*DD; i += 128) lw1[i] = (double)w1[i];
  for (int i = tid; i < DD*DD; i += 128) lw2[i] = (double)w2[i];
  if (tid < DD){ lb1[tid] = (double)b1[tid]; lb2[tid] = (double)b2[tid]; }
  __syncthreads();

  int nl = tid >> 2, q = tid & 3;
  int node = nodeBase + nl;
  const float* xr = x + (size_t)node * INC;
  double acc[8];
#pragma unroll
  for (int c = 0; c < 8; ++c) acc[c] = lb1[q*8 + c];
#pragma unroll 8
  for (int k = 0; k < INC; ++k){
    double xv = (double)xr[k];
#pragma unroll
    for (int c = 0; c < 8; ++c) acc[c] = fma(xv, lw1[k*DD + q*8 + c], acc[c]);
  }
  double h1o[8];
#pragma unroll
  for (int c = 0; c < 8; ++c) h1o[c] = elud(acc[c]);
  double h1f[DD];
#pragma unroll
  for (int b = 0; b < 4; ++b){
#pragma unroll
    for (int i = 0; i < 8; ++i)
      h1f[b*8 + i] = __shfl_xor(h1o[i], q ^ b);
  }
#pragma unroll
  for (int c = 0; c < 8; ++c) acc[c] = lb2[q*8 + c];
#pragma unroll 8
  for (int k = 0; k < DD; ++k){
    double hk = h1f[k];
#pragma unroll
    for (int c = 0; c < 8; ++c) acc[c] = fma(hk, lw2[k*DD + q*8 + c], acc[c]);
  }
  double h2[8];
#pragma unroll
  for (int c = 0; c < 8; ++c) h2[c] = elud(acc[c]);
  double* hT = (double*)(ws + OB_H64);
#pragma unroll
  for (int c = 0; c < 8; ++c) hT[(size_t)(q*8 + c)*NN + node] = h2[c];

  double s[8], qv[8];
#pragma unroll
  for (int i = 0; i < 8; ++i){ s[i] = h2[i]; qv[i] = h2[i]*h2[i]; }
#pragma unroll
  for (int o = 4; o <= 32; o <<= 1){
#pragma unroll
    for (int i = 0; i < 8; ++i){ s[i] += __shfl_xor(s[i], o); qv[i] += __shfl_xor(qv[i], o); }
  }
  int lane = tid & 63, wid = tid >> 6;
  if (lane < 4){
#pragma unroll
    for (int i = 0; i < 8; ++i){
      wpart[wid][lane*8 + i]      = s[i];
      wpart[wid][32 + lane*8 + i] = qv[i];
    }
  }
  __syncthreads();
  if (tid < 64)
    ((double*)(ws + OB_P1))[blockIdx.x*64 + tid] = wpart[0][tid] + wpart[1][tid];
}

__global__ __launch_bounds__(128) void k_stats(const double* __restrict__ part,
    double* __restrict__ stats, int nrows)
{
  __shared__ double ls[128], lq[128];
  int c = blockIdx.x;
  int t = threadIdx.x;
  double s = 0.0, q = 0.0;
  for (int r = t; r < nrows; r += 128){
    s += part[r*64 + c];
    q += part[r*64 + 32 + c];
  }
  ls[t] = s; lq[t] = q;
  __syncthreads();
  for (int o = 64; o > 0; o >>= 1){
    if (t < o){ ls[t] += ls[t+o]; lq[t] += lq[t+o]; }
    __syncthreads();
  }
  if (t == 0){
    double m = ls[0] / (double)NN;
    double qq = lq[0] / (double)NN;
    stats[c] = m;
    stats[32+c] = 1.0 / sqrt(qq - m*m + EPSV);
  }
}

// 2 threads/node: BN1 in-register, exact f64 s-chains, feat halves;
// s32 written as float4 (x,y,z,r).
__global__ __launch_bounds__(128) void k_sfeat(
    const float* __restrict__ sw, const float* __restrict__ sb,
    const float* __restrict__ hw, const float* __restrict__ hb,
    const float* __restrict__ g, const float* __restrict__ b,
    char* __restrict__ ws)
{
  __shared__ double lsw[DD*3], lsb[3], lstat[64], lgd[DD], lbd[DD];
  __shared__ float lhw[DD*DD], lhb[DD];
  int tid = threadIdx.x;
  for (int i = tid; i < DD*3; i += 128) lsw[i] = (double)sw[i];
  for (int i = tid; i < DD*DD; i += 128) lhw[i] = hw[i];
  if (tid < 3) lsb[tid] = (double)sb[tid];
  if (tid < DD){ lhb[tid] = hb[tid]; lgd[tid] = (double)g[tid]; lbd[tid] = (double)b[tid]; }
  if (tid >= 64 && tid < 128) lstat[tid-64] = ((const double*)(ws + OB_ST1))[tid-64];
  __syncthreads();
  int nl = tid >> 1, p = tid & 1;
  int node = blockIdx.x*64 + nl;
  const double* hT = (const double*)(ws + OB_H64);
  double ho[16];
#pragma unroll
  for (int i = 0; i < 16; ++i){
    int c = p*16 + i;
    double xv = hT[(size_t)c*NN + node];
    ho[i] = (xv - lstat[c]) * lstat[32+c] * lgd[c] + lbd[c];
  }
  double hf[DD];
#pragma unroll
  for (int i = 0; i < 16; ++i){
    double pr = __shfl_xor(ho[i], 1);
    hf[i]      = p ? pr : ho[i];
    hf[16 + i] = p ? ho[i] : pr;
  }
  double* sT = (double*)(ws + OB_S64);
  double v0 = 0.0, v1 = 0.0, v2 = 0.0;
  if (p == 0){
    double s0 = lsb[0], s2 = lsb[2];
#pragma unroll
    for (int k = 0; k < DD; ++k){
      s0 = fma(hf[k], lsw[k*3+0], s0);
      s2 = fma(hf[k], lsw[k*3+2], s2);
    }
    sT[node] = s0; sT[2*NN + node] = s2;
    v0 = s0; v2 = s2;
  } else {
    double s1 = lsb[1];
#pragma unroll
    for (int k = 0; k < DD; ++k) s1 = fma(hf[k], lsw[k*3+1], s1);
    sT[NN + node] = s1;
    v1 = s1;
  }
  {
    float f0 = (float)v0, f1 = (float)v1, f2 = (float)v2;
    float g0 = __shfl_xor(f0, 1);
    float g2 = __shfl_xor(f2, 1);
    if (p == 1){
      float r = fmaf(g2, g2, fmaf(f1, f1, g0*g0));
      ((float4*)(ws + OB_S32))[node] = make_float4(g0, f1, g2, r);
    }
  }
  float hv[DD];
#pragma unroll
  for (int c = 0; c < DD; ++c) hv[c] = (float)hf[c];
  float f[16];
#pragma unroll
  for (int i = 0; i < 16; ++i) f[i] = lhb[p*16 + i];
#pragma unroll 4
  for (int k = 0; k < DD; ++k){
    float hk = hv[k];
#pragma unroll
    for (int i = 0; i < 16; ++i) f[i] = fmaf(hk, lhw[k*DD + p*16 + i], f[i]);
  }
  float* frow = (float*)(ws + OB_F32) + (size_t)node*DD + p*16;
#pragma unroll
  for (int u = 0; u < 4; ++u)
    ((float4*)frow)[u] = make_float4(f[4*u], f[4*u+1], f[4*u+2], f[4*u+3]);
}

// one wave per query node. Stage A: f32 prefilter superset (window [40,58]).
// Stage B: exact f64 refine with fast paths (cnt==40 / cLE==40 / full).
__global__ __launch_bounds__(256) void k_knn(char* __restrict__ ws)
{
  __shared__ int   lds_cand[4][64];
  __shared__ int   lds_j[4][KK];
  __shared__ float lds_w[4][KK];
  const double* sT = (const double*)(ws + OB_S64);
  const float*  fp = (const float*)(ws + OB_F32);
  float* ap = (float*)(ws + OB_A32);
  int tid = threadIdx.x;
  int lane = tid & 63, wid = tid >> 6;
  int n = blockIdx.x * 4 + wid;
  int e = n / PP;
  int base = e * PP;
  const float4* s4 = (const float4*)(ws + OB_S32) + base;
  int nl = n - base;
  float4 qv = s4[nl];
  float m2x = -2.f*qv.x, m2y = -2.f*qv.y, m2z = -2.f*qv.z;
  float rq = qv.w;

  float d2f[16];
#pragma unroll
  for (int t = 0; t < 16; ++t){
    int j = lane + 64*t;
    float key = __builtin_inff();
    if (j < PP){
      float4 p = s4[j];
      float u = fmaf(p.x, m2x, p.w);
      u = fmaf(p.y, m2y, u);
      u = fmaf(p.z, m2z, u);
      key = fmaxf(u + rq, 0.f);
    }
    d2f[t] = key;
  }
  float lmin = d2f[0];
#pragma unroll
  for (int t = 1; t < 16; ++t) lmin = fminf(lmin, d2f[t]);
  float glo = lmin, ghi = lmin;
#pragma unroll
  for (int o = 32; o > 0; o >>= 1){
    glo = fminf(glo, __shfl_xor(glo, o));
    ghi = fmaxf(ghi, __shfl_xor(ghi, o));
  }
  unsigned lo = __float_as_uint(glo), hi = __float_as_uint(ghi);
  while (lo < hi){
    unsigned mid = lo + ((hi - lo) >> 1);
    float midf = __uint_as_float(mid);
    int c = 0;
#pragma unroll
    for (int t = 0; t < 16; ++t) c += __popcll(__ballot(d2f[t] <= midf));
    if (c >= KK){
      if (c <= 58){ lo = mid; break; }
      hi = mid;
    } else lo = mid + 1;
  }
  float T = __uint_as_float(lo) * 1.0015f + 4e-6f;

  unsigned long long lml = (1ull << lane) - 1ull;
  int cnt = 0;
#pragma unroll
  for (int t = 0; t < 16; ++t){
    bool sel = d2f[t] <= T;
    unsigned long long m = __ballot(sel);
    if (sel){
      int pos = cnt + __popcll(m & lml);
      if (pos < 64) lds_cand[wid][pos] = lane + 64*t;
    }
    cnt += __popcll(m);
  }
  if (cnt > 64) cnt = 64;

  double sx = sT[n], sy = sT[NN + n], sz = sT[2*NN + n];
  int jl = (lane < cnt) ? lds_cand[wid][lane] : -1;
  double d2l = __builtin_inf();
  if (jl >= 0){
    int jj = base + jl;
    double dx = sT[jj] - sx, dy = sT[NN + jj] - sy, dz = sT[2*NN + jj] - sz;
    d2l = (dx*dx + dy*dy) + dz*dz;   // np summation order (matches ref chain)
  }
  bool sel40;
  if (cnt == KK){
    sel40 = (jl >= 0);
  } else {
    unsigned long long bits = (unsigned long long)__double_as_longlong(d2l);
    unsigned khi = (unsigned)(bits >> 32);
    unsigned klo = (unsigned)bits;
    unsigned blo = (jl >= 0) ? khi : 0xFFFFFFFFu;
    unsigned bhi = (jl >= 0) ? khi : 0u;
#pragma unroll
    for (int o = 32; o > 0; o >>= 1){
      blo = min(blo, (unsigned)__shfl_xor((int)blo, o));
      bhi = max(bhi, (unsigned)__shfl_xor((int)bhi, o));
    }
    unsigned l1 = blo, h1 = bhi;
    while (l1 < h1){
      unsigned mid = l1 + ((h1 - l1) >> 1);
      int c = __popcll(__ballot(khi <= mid));
      if (c >= KK) h1 = mid; else l1 = mid + 1;
    }
    unsigned H2 = l1;
    int cLE = __popcll(__ballot(khi <= H2));
    if (cLE == KK){
      sel40 = (jl >= 0) && (khi <= H2);
    } else {
      int cLT = __popcll(__ballot(khi < H2));
      int r = KK - cLT;
      unsigned l2 = 0u, h2v = 0xFFFFFFFFu;
      while (l2 < h2v){
        unsigned mid = l2 + ((h2v - l2) >> 1);
        int c = __popcll(__ballot(khi == H2 && klo <= mid));
        if (c >= r) h2v = mid; else l2 = mid + 1;
      }
      unsigned L2v = l2;
      int cLT2 = __popcll(__ballot(khi == H2 && klo < L2v));
      int r2 = r - cLT2;
      bool dup = (khi == H2) && (klo == L2v);
      unsigned long long dupm = __ballot(dup);
      int rank = 0;
      if (dup){
        unsigned long long mm = dupm;
        while (mm){
          int l = __builtin_ctzll(mm);
          mm &= mm - 1;
          if (lds_cand[wid][l] < jl) rank++;
        }
      }
      sel40 = (khi < H2) || (khi == H2 && klo < L2v) || (dup && rank < r2);
    }
  }
  unsigned long long selm = __ballot(sel40);
  if (sel40){
    int pos = __popcll(selm & lml);
    lds_j[wid][pos] = jl;
    lds_w[wid][pos] = expf(-10.f * (float)d2l);
  }

  int half = lane >> 5, ch = lane & 31;
  float accm = 0.f, accx = -__builtin_inff();
#pragma unroll
  for (int c0 = 0; c0 < 2; ++c0){
    float fv[10], wv[10];
#pragma unroll
    for (int it = 0; it < 10; ++it){
      int si = 2*(c0*10 + it) + half;
      int j = lds_j[wid][si];
      wv[it] = lds_w[wid][si];
      fv[it] = fp[((base + j) << 5) + ch];
    }
#pragma unroll
    for (int it = 0; it < 10; ++it){
      float m = wv[it] * fv[it];
      accm += m;
      accx = fmaxf(accx, m);
    }
  }
  accm += __shfl_xor(accm, 32);
  accx = fmaxf(accx, __shfl_xor(accx, 32));
  if (lane < DD){
    ap[(size_t)n*64 + lane]      = accm * (1.f/KK);
    ap[(size_t)n*64 + DD + lane] = accx;
  }
}

// 1 thread/node: BN1 re-applied from ST1, xgn in registers, post-MLP,
// BN2 partials (half-split butterfly). Weights staged in LDS (round-12 form;
// round-13's global-weight variant regressed: per-lane VMEM >> ds_read).
__global__ __launch_bounds__(128) void k_post(
    const float* __restrict__ g, const float* __restrict__ b,
    const float* __restrict__ o1w, const float* __restrict__ o2w,
    const float* __restrict__ o2b,
    const float* __restrict__ p1w, const float* __restrict__ p1b,
    const float* __restrict__ p2w, const float* __restrict__ p2b,
    char* __restrict__ ws)
{
  __shared__ float l1[DD*DD], l2[2*DD*DD], lp1[67*DD], lp2[DD*DD];
  __shared__ float l2b[DD], lp1b[DD], lp2b[DD];
  __shared__ double lstat[64], lgd[DD], lbd[DD];
  __shared__ double wpart[2][64];
  int tid = threadIdx.x;
  for (int i = tid; i < DD*DD; i += 128) l1[i] = o1w[i];
  for (int i = tid; i < 2*DD*DD; i += 128) l2[i] = o2w[i];
  for (int i = tid; i < 67*DD; i += 128) lp1[i] = p1w[i];
  for (int i = tid; i < DD*DD; i += 128) lp2[i] = p2w[i];
  if (tid < DD){ l2b[tid] = o2b[tid]; lp1b[tid] = p1b[tid]; lp2b[tid] = p2b[tid];
                 lgd[tid] = (double)g[tid]; lbd[tid] = (double)b[tid]; }
  if (tid >= 64 && tid < 128) lstat[tid-64] = ((const double*)(ws + OB_ST1))[tid-64];
  __syncthreads();
  int node = blockIdx.x*128 + tid;
  const double* hT = (const double*)(ws + OB_H64);
  float hv[DD];
#pragma unroll 4
  for (int c = 0; c < DD; ++c){
    double xv = hT[(size_t)c*NN + node];
    hv[c] = (float)((xv - lstat[c]) * lstat[32+c] * lgd[c] + lbd[c]);
  }
  float xg[DD];
#pragma unroll
  for (int c = 0; c < DD; ++c) xg[c] = l2b[c];
#pragma unroll 4
  for (int k = 0; k < DD; ++k){
    float hk = hv[k];
#pragma unroll
    for (int c = 0; c < DD; ++c) xg[c] = fmaf(hk, l1[k*DD+c], xg[c]);
  }
  const float4* ar = (const float4*)((const float*)(ws + OB_A32) + (size_t)node*64);
#pragma unroll 2
  for (int k4 = 0; k4 < 16; ++k4){
    float4 a = ar[k4];
    float as[4] = {a.x, a.y, a.z, a.w};
#pragma unroll
    for (int u = 0; u < 4; ++u){
      int k = k4*4 + u;
#pragma unroll
      for (int c = 0; c < DD; ++c) xg[c] = fmaf(as[u], l2[k*DD+c], xg[c]);
    }
  }
  float t1[DD];
#pragma unroll
  for (int c = 0; c < DD; ++c) t1[c] = lp1b[c];
#pragma unroll 4
  for (int k = 0; k < DD; ++k){
    float v = xg[k];
#pragma unroll
    for (int c = 0; c < DD; ++c) t1[c] = fmaf(v, lp1[k*DD+c], t1[c]);
  }
  {
    const double* sT = (const double*)(ws + OB_S64);
    float s0 = (float)sT[node], s1 = (float)sT[NN+node], s2 = (float)sT[2*NN+node];
#pragma unroll
    for (int c = 0; c < DD; ++c){
      t1[c] = fmaf(s0, lp1[32*DD+c], t1[c]);
      t1[c] = fmaf(s1, lp1[33*DD+c], t1[c]);
      t1[c] = fmaf(s2, lp1[34*DD+c], t1[c]);
    }
  }
#pragma unroll 4
  for (int k = 0; k < DD; ++k){
    float v = hv[k];
#pragma unroll
    for (int c = 0; c < DD; ++c) t1[c] = fmaf(v, lp1[(35+k)*DD+c], t1[c]);
  }
#pragma unroll
  for (int c = 0; c < DD; ++c) t1[c] = eluf(t1[c]);
  float t2[DD];
#pragma unroll
  for (int c = 0; c < DD; ++c) t2[c] = lp2b[c];
#pragma unroll 4
  for (int k = 0; k < DD; ++k){
    float v = t1[k];
#pragma unroll
    for (int c = 0; c < DD; ++c) t2[c] = fmaf(v, lp2[k*DD+c], t2[c]);
  }
#pragma unroll
  for (int c = 0; c < DD; ++c) t2[c] = eluf(t2[c]);
  float* tr = (float*)(ws + OB_F32) + (size_t)node*DD;
#pragma unroll
  for (int u = 0; u < 8; ++u)
    ((float4*)tr)[u] = make_float4(t2[4*u], t2[4*u+1], t2[4*u+2], t2[4*u+3]);

  int lane = tid & 63, wid = tid >> 6;
#pragma unroll
  for (int hlf = 0; hlf < 2; ++hlf){
    double s[16], q[16];
#pragma unroll
    for (int i = 0; i < 16; ++i){ double xv = (double)t2[hlf*16 + i]; s[i] = xv; q[i] = xv*xv; }
#pragma unroll
    for (int o = 32; o > 0; o >>= 1){
#pragma unroll
      for (int i = 0; i < 16; ++i){ s[i] += __shfl_xor(s[i], o); q[i] += __shfl_xor(q[i], o); }
    }
    if (lane == 0){
#pragma unroll
      for (int i = 0; i < 16; ++i){
        wpart[wid][hlf*16 + i] = s[i];
        wpart[wid][32 + hlf*16 + i] = q[i];
      }
    }
  }
  __syncthreads();
  if (tid < 64)
    ((double*)(ws + OB_P2))[blockIdx.x*64 + tid] = wpart[0][tid] + wpart[1][tid];
}

__global__ __launch_bounds__(256) void k_bnout(
    const float* __restrict__ g, const float* __restrict__ b,
    const char* __restrict__ ws, float* __restrict__ out)
{
  __shared__ float lstat[64], lg[DD], lb[DD];
  int tid = threadIdx.x;
  if (tid < 64) lstat[tid] = (float)((const double*)(ws + OB_ST2))[tid];
  if (tid >= 64 && tid < 96){ lg[tid-64] = g[tid-64]; lb[tid-64] = b[tid-64]; }
  __syncthreads();
  int node = blockIdx.x*256 + tid;
  const float4* tr = (const float4*)((const float*)(ws + OB_F32) + (size_t)node*DD);
  float4* orow = (float4*)(out + (size_t)node*DD);
#pragma unroll
  for (int i = 0; i < 8; ++i){
    float4 v = tr[i];
    float vv[4] = {v.x, v.y, v.z, v.w};
#pragma unroll
    for (int u = 0; u < 4; ++u){
      int c = 4*i + u;
      vv[u] = (vv[u] - lstat[c]) * lstat[32+c] * lg[c] + lb[c];
    }
    orow[i] = make_float4(vv[0], vv[1], vv[2], vv[3]);
  }
}

extern "C" void kernel_launch(void* const* d_in, const int* in_sizes, int n_in,
                              void* d_out, int out_size, void* d_ws, size_t ws_size,
                              hipStream_t stream)
{
  const float* x       = (const float*)d_in[0];
  const float* pre_w1  = (const float*)d_in[3];
  const float* pre_b1  = (const float*)d_in[4];
  const float* pre_w2  = (const float*)d_in[5];
  const float* pre_b2  = (const float*)d_in[6];
  const float* bn1_g   = (const float*)d_in[7];
  const float* bn1_b   = (const float*)d_in[8];
  const float* lin_s_w = (const float*)d_in[9];
  const float* lin_s_b = (const float*)d_in[10];
  const float* lin_h_w = (const float*)d_in[11];
  const float* lin_h_b = (const float*)d_in[12];
  const float* out1_w  = (const float*)d_in[13];
  const float* out2_w  = (const float*)d_in[14];
  const float* out2_b  = (const float*)d_in[15];
  const float* post_w1 = (const float*)d_in[16];
  const float* post_b1 = (const float*)d_in[17];
  const float* post_w2 = (const float*)d_in[18];
  const float* post_b2 = (const float*)d_in[19];
  const float* bn2_g   = (const float*)d_in[20];
  const float* bn2_b   = (const float*)d_in[21];
  char* ws  = (char*)d_ws;
  float* out = (float*)d_out;

  k_pre  <<<1000, 128, 0, stream>>>(x, pre_w1, pre_b1, pre_w2, pre_b2, ws);
  k_stats<<<32, 128, 0, stream>>>((const double*)(ws + OB_P1), (double*)(ws + OB_ST1), 1000);
  k_sfeat<<<500, 128, 0, stream>>>(lin_s_w, lin_s_b, lin_h_w, lin_h_b, bn1_g, bn1_b, ws);
  k_knn  <<<8000, 256, 0, stream>>>(ws);
  k_post <<<250, 128, 0, stream>>>(bn1_g, bn1_b, out1_w, out2_w, out2_b,
                                   post_w1, post_b1, post_w2, post_b2, ws);
  k_stats<<<32, 128, 0, stream>>>((const double*)(ws + OB_P2), (double*)(ws + OB_ST2), 250);
  k_bnout<<<125, 256, 0, stream>>>(bn2_g, bn2_b, ws, out);
}